// Round 5
// baseline (278.999 us; speedup 1.0000x reference)
//
#include <hip/hip_runtime.h>

#define NN 50000
#define NE 800000
#define IND 32
#define DD 16
#define BB 8
#define NC 128   // BB*DD
#define EPSBN 1e-5f
#define SCB ((NN + 255) / 256)   // 196 scan blocks
#define G 128                    // histogram blocks per direction
#define CHE (NE / G)             // 6250 edges per hist block
#define WPN (NN / 4)             // 12500 packed words (4 uint8 counters each)
#define SHSZ 12500               // src-shard width (Hb shard = 3.2 MB, fits 4 MB XCD L2)

typedef unsigned int uint;
typedef unsigned short ushort;
typedef unsigned long long ull;

__device__ __forceinline__ ushort f2bf(float f) {
  uint u = __float_as_uint(f);
  return (ushort)((u + 0x7fffu + ((u >> 16) & 1u)) >> 16);  // RNE
}
__device__ __forceinline__ uint pack2bf(float lo, float hi) {
  return (uint)f2bf(lo) | ((uint)f2bf(hi) << 16);
}

// Per-block LDS histogram (uint8 packed 4/word). blocks [0,G): dst, [G,2G): src.
__global__ __launch_bounds__(256) void k_hist(const int* __restrict__ src,
                                              const int* __restrict__ dst,
                                              uint* __restrict__ dstH,
                                              uint* __restrict__ srcH) {
  __shared__ uint h[WPN];  // 50 KB
  int b = blockIdx.x;
  bool isDst = b < G;
  int cb = isDst ? b : b - G;
  const int* idx = isDst ? dst : src;
  uint* out = (isDst ? dstH : srcH) + (size_t)cb * WPN;
  for (int w = threadIdx.x; w < WPN; w += 256) h[w] = 0;
  __syncthreads();
  int base = cb * CHE;
  for (int k = threadIdx.x; k < CHE; k += 256) {
    int d = idx[base + k];
    atomicAdd(&h[d >> 2], 1u << ((d & 3) * 8));
  }
  __syncthreads();
  for (int w = threadIdx.x; w < WPN; w += 256) out[w] = h[w];
}

// Column-reduce the per-block histograms. dst side: also convert dstH in place
// to exclusive per-block byte-prefixes (carry-free packed add: counts <= ~45).
__global__ __launch_bounds__(256) void k_reduce(uint* __restrict__ dstH,
                                                const uint* __restrict__ srcH,
                                                int* __restrict__ degi,
                                                float* __restrict__ inorm,
                                                float* __restrict__ onorm) {
  int b = blockIdx.x;
  bool isDst = b < 49;
  int col = (isDst ? b : b - 49) * 256 + threadIdx.x;
  if (col >= WPN) return;
  if (isDst) {
    uint run = 0;
    for (int k = 0; k < G; k++) {
      size_t p = (size_t)k * WPN + col;
      uint v = dstH[p];
      dstH[p] = run;   // exclusive prefix (packed bytes)
      run += v;
    }
    int n0 = col * 4;
    int4 dv;
    float4 nv;
    int c0 = run & 255, c1 = (run >> 8) & 255, c2 = (run >> 16) & 255, c3 = (run >> 24) & 255;
    dv.x = c0; dv.y = c1; dv.z = c2; dv.w = c3;
    nv.x = rsqrtf((float)(c0 > 1 ? c0 : 1));
    nv.y = rsqrtf((float)(c1 > 1 ? c1 : 1));
    nv.z = rsqrtf((float)(c2 > 1 ? c2 : 1));
    nv.w = rsqrtf((float)(c3 > 1 ? c3 : 1));
    *(int4*)(degi + n0) = dv;
    *(float4*)(inorm + n0) = nv;
  } else {
    uint run = 0;
    for (int k = 0; k < G; k++) run += srcH[(size_t)k * WPN + col];
    int n0 = col * 4;
    float4 nv;
    int c0 = run & 255, c1 = (run >> 8) & 255, c2 = (run >> 16) & 255, c3 = (run >> 24) & 255;
    nv.x = rsqrtf((float)(c0 > 1 ? c0 : 1));
    nv.y = rsqrtf((float)(c1 > 1 ? c1 : 1));
    nv.z = rsqrtf((float)(c2 > 1 ? c2 : 1));
    nv.w = rsqrtf((float)(c3 > 1 ? c3 : 1));
    *(float4*)(onorm + n0) = nv;
  }
}

// ---- hierarchical exclusive scan of degi -> off ----
__global__ void k_scan1(const int* __restrict__ degi, int* __restrict__ bsum) {
  __shared__ int sh[256];
  int n = blockIdx.x * 256 + threadIdx.x;
  sh[threadIdx.x] = (n < NN) ? degi[n] : 0;
  __syncthreads();
  for (int o = 128; o > 0; o >>= 1) {
    if (threadIdx.x < o) sh[threadIdx.x] += sh[threadIdx.x + o];
    __syncthreads();
  }
  if (threadIdx.x == 0) bsum[blockIdx.x] = sh[0];
}

__global__ void k_scan2(const int* __restrict__ bsum, int* __restrict__ boff) {
  __shared__ int sh[256];
  int t = threadIdx.x;
  int v = (t < SCB) ? bsum[t] : 0;
  sh[t] = v;
  __syncthreads();
  for (int o = 1; o < 256; o <<= 1) {
    int u = (t >= o) ? sh[t - o] : 0;
    __syncthreads();
    sh[t] += u;
    __syncthreads();
  }
  if (t < SCB) boff[t] = sh[t] - v;  // exclusive
}

__global__ void k_scan3(const int* __restrict__ degi, const int* __restrict__ boff,
                        int* __restrict__ off) {
  __shared__ int sh[256];
  int n = blockIdx.x * 256 + threadIdx.x;
  int t = threadIdx.x;
  int v = (n < NN) ? degi[n] : 0;
  sh[t] = v;
  __syncthreads();
  for (int o = 1; o < 256; o <<= 1) {
    int u = (t >= o) ? sh[t - o] : 0;
    __syncthreads();
    sh[t] += u;
    __syncthreads();
  }
  if (n < NN) off[n] = boff[blockIdx.x] + sh[t] - v;
}

// CSR build with NO global atomics: pos = off[d] + byte-prefix(block) + LDS rank.
__global__ __launch_bounds__(512) void k_csr2(const int* __restrict__ src,
                                              const int* __restrict__ dst,
                                              const int* __restrict__ off,
                                              const uint* __restrict__ dstH,
                                              ushort* __restrict__ csr) {
  __shared__ uint cur[WPN];  // 50 KB byte cursors
  int b = blockIdx.x;
  for (int w = threadIdx.x; w < WPN; w += 512) cur[w] = 0;
  __syncthreads();
  const uint* bb = dstH + (size_t)b * WPN;
  int base = b * CHE;
  for (int k = threadIdx.x; k < CHE; k += 512) {
    int e = base + k;
    int d = dst[e];
    int sh = (d & 3) * 8;
    uint old = atomicAdd(&cur[d >> 2], 1u << sh);
    int rank = (old >> sh) & 255;
    int pre = (bb[d >> 2] >> sh) & 255;
    csr[off[d] + pre + rank] = (ushort)src[e];
  }
}

// Regroup each node's neighbor list by src shard (wave-ballot counting sort).
// One wave per node; emits csr2 (shard-grouped) + per-node shard boundaries sb.
__global__ __launch_bounds__(256) void k_shard(const int* __restrict__ off,
                                               const int* __restrict__ degi,
                                               const ushort* __restrict__ csr,
                                               ushort* __restrict__ csrS,
                                               ushort4* __restrict__ sb) {
  int n = blockIdx.x * 4 + (threadIdx.x >> 6);
  int lane = threadIdx.x & 63;
  int o = off[n], dg = degi[n];
  int c0 = 0, c1 = 0, c2 = 0;
  for (int base = 0; base < dg; base += 64) {
    int j = base + lane;
    int s = (j < dg) ? (int)csr[o + j] / SHSZ : -1;
    c0 += __popcll(__ballot(s == 0));
    c1 += __popcll(__ballot(s == 1));
    c2 += __popcll(__ballot(s == 2));
  }
  int q0 = 0, q1 = c0, q2 = c0 + c1, q3 = c0 + c1 + c2;
  for (int base = 0; base < dg; base += 64) {
    int j = base + lane;
    bool v = j < dg;
    int e = v ? (int)csr[o + j] : 0;
    int s = v ? e / SHSZ : -1;
    ull m0 = __ballot(s == 0), m1 = __ballot(s == 1);
    ull m2 = __ballot(s == 2), m3 = __ballot(s == 3);
    ull lt = ((ull)1 << lane) - 1;
    if (v) {
      int pos = (s == 0) ? q0 + __popcll(m0 & lt)
              : (s == 1) ? q1 + __popcll(m1 & lt)
              : (s == 2) ? q2 + __popcll(m2 & lt)
                         : q3 + __popcll(m3 & lt);
      csrS[o + pos] = (ushort)e;
    }
    q0 += __popcll(m0); q1 += __popcll(m1);
    q2 += __popcll(m2); q3 += __popcll(m3);
  }
  if (lane == 0)
    sb[n] = make_ushort4((ushort)c0, (ushort)(c0 + c1), (ushort)(c0 + c1 + c2), (ushort)dg);
}

// H (bf16, node-major [n][128]) = (x @ W1) * onorm
__global__ void k_gemm1(const float* __restrict__ x, const float* __restrict__ W1,
                        const float* __restrict__ onorm, ushort* __restrict__ Hb) {
  __shared__ float w[IND * DD];
  int tid = threadIdx.x;
  for (int i = tid; i < IND * DD; i += 256) w[i] = W1[i];
  __syncthreads();
  int gid = blockIdx.x * 256 + tid;  // gid = b*NN + n
  if (gid >= BB * NN) return;
  int b = gid / NN;
  int n = gid - b * NN;
  const float* xb = x + (size_t)b * IND * NN + n;
  float acc[DD];
#pragma unroll
  for (int d = 0; d < DD; d++) acc[d] = 0.f;
  for (int i = 0; i < IND; i++) {
    float v = xb[(size_t)i * NN];
#pragma unroll
    for (int d = 0; d < DD; d++) acc[d] = fmaf(v, w[i * DD + d], acc[d]);
  }
  float on = onorm[n];
  uint p[8];
#pragma unroll
  for (int k = 0; k < 8; k++) p[k] = pack2bf(acc[2 * k] * on, acc[2 * k + 1] * on);
  uint* o4 = (uint*)(Hb + ((size_t)n * BB + b) * DD);
  *(uint4*)(o4) = make_uint4(p[0], p[1], p[2], p[3]);
  *(uint4*)(o4 + 4) = make_uint4(p[4], p[5], p[6], p[7]);
}

// AGG[n][0:128] (fp32) = sum over in-edges of Hb[src][0:128] (bf16),
// iterated shard-by-shard so concurrent waves share a 3.2 MB L2 working set.
__global__ void k_gather(const int* __restrict__ off, const ushort4* __restrict__ sb,
                         const ushort* __restrict__ csrS, const ushort* __restrict__ Hb,
                         float* __restrict__ AGG) {
  int gid = blockIdx.x * 256 + threadIdx.x;
  int n = gid >> 4;
  if (n >= NN) return;
  int q = (gid & 15) * 8;  // 8 bf16 columns per lane, 16 lanes per node
  int o = off[n];
  ushort4 s4 = sb[n];
  float acc[8];
#pragma unroll
  for (int k = 0; k < 8; k++) acc[k] = 0.f;
  int lo = 0;
#pragma unroll
  for (int sh = 0; sh < 4; sh++) {
    int hi = (sh == 0) ? s4.x : (sh == 1) ? s4.y : (sh == 2) ? s4.z : s4.w;
    for (int j = lo; j < hi; j++) {
      int s = csrS[o + j];
      uint4 v = *(const uint4*)(Hb + (size_t)s * NC + q);
      acc[0] += __uint_as_float(v.x << 16);
      acc[1] += __uint_as_float(v.x & 0xffff0000u);
      acc[2] += __uint_as_float(v.y << 16);
      acc[3] += __uint_as_float(v.y & 0xffff0000u);
      acc[4] += __uint_as_float(v.z << 16);
      acc[5] += __uint_as_float(v.z & 0xffff0000u);
      acc[6] += __uint_as_float(v.w << 16);
      acc[7] += __uint_as_float(v.w & 0xffff0000u);
    }
    lo = hi;
  }
  float* op = AGG + (size_t)n * NC + q;
  *(float4*)(op) = make_float4(acc[0], acc[1], acc[2], acc[3]);
  *(float4*)(op + 4) = make_float4(acc[4], acc[5], acc[6], acc[7]);
}

// per-column sums of a = AGG*inorm  (for BN stats)
__global__ void k_stats(const float* __restrict__ AGG, const float* __restrict__ inorm,
                        float* __restrict__ sum, float* __restrict__ sumsq) {
  __shared__ float sh[256];
  int c = threadIdx.x & (NC - 1);
  int r = threadIdx.x >> 7;
  float s = 0.f, ss = 0.f;
  for (int n = blockIdx.x * 2 + r; n < NN; n += gridDim.x * 2) {
    float a = AGG[(size_t)n * NC + c] * inorm[n];
    s += a;
    ss = fmaf(a, a, ss);
  }
  sh[threadIdx.x] = s;
  __syncthreads();
  if (r == 0) unsafeAtomicAdd(&sum[c], s + sh[threadIdx.x + 128]);
  __syncthreads();
  sh[threadIdx.x] = ss;
  __syncthreads();
  if (r == 0) unsafeAtomicAdd(&sumsq[c], ss + sh[threadIdx.x + 128]);
}

// fold BN (+ bias cancellation) into per-column scale/shift
__global__ void k_prep(const float* __restrict__ sum, const float* __restrict__ sumsq,
                       const float* __restrict__ gamma, const float* __restrict__ beta,
                       float* __restrict__ sc, float* __restrict__ tc) {
  int c = threadIdx.x;
  if (c < NC) {
    float mu = sum[c] * (1.0f / NN);
    float var = fmaxf(sumsq[c] * (1.0f / NN) - mu * mu, 0.f);
    int d = c & (DD - 1);
    float s = gamma[d] * rsqrtf(var + EPSBN);
    sc[c] = s;
    tc[c] = beta[d] - mu * s;
  }
}

// Hb = bf16((relu(bn1(AGG*inorm)) @ W2) * onorm)   -- fused BN1+ReLU+GEMM2
__global__ void k_applyg2(const float* __restrict__ AGG, const float* __restrict__ inorm,
                          const float* __restrict__ onorm, const float* __restrict__ sc,
                          const float* __restrict__ tc, const float* __restrict__ W2,
                          ushort* __restrict__ Hb) {
  __shared__ float w[DD * DD];
  __shared__ float ssc[NC], stc[NC];
  int tid = threadIdx.x;
  if (tid < DD * DD) w[tid] = W2[tid];
  if (tid < NC) { ssc[tid] = sc[tid]; stc[tid] = tc[tid]; }
  __syncthreads();
  int gid = blockIdx.x * 256 + tid;  // gid = n*8 + b
  if (gid >= BB * NN) return;
  int n = gid >> 3, b = gid & 7;
  const float4* ap = (const float4*)(AGG + (size_t)gid * DD);
  float inn = inorm[n];
  float z[DD];
  float4 v0 = ap[0], v1 = ap[1], v2 = ap[2], v3 = ap[3];
  z[0] = v0.x; z[1] = v0.y; z[2] = v0.z; z[3] = v0.w;
  z[4] = v1.x; z[5] = v1.y; z[6] = v1.z; z[7] = v1.w;
  z[8] = v2.x; z[9] = v2.y; z[10] = v2.z; z[11] = v2.w;
  z[12] = v3.x; z[13] = v3.y; z[14] = v3.z; z[15] = v3.w;
#pragma unroll
  for (int d = 0; d < DD; d++) {
    int c = b * DD + d;
    z[d] = fmaxf(0.f, fmaf(z[d] * inn, ssc[c], stc[c]));
  }
  float on = onorm[n];
  float o[DD];
#pragma unroll
  for (int d2 = 0; d2 < DD; d2++) {
    float acc = 0.f;
#pragma unroll
    for (int d = 0; d < DD; d++) acc = fmaf(z[d], w[d * DD + d2], acc);
    o[d2] = acc * on;
  }
  uint p[8];
#pragma unroll
  for (int k = 0; k < 8; k++) p[k] = pack2bf(o[2 * k], o[2 * k + 1]);
  uint* op = (uint*)(Hb + (size_t)gid * DD);
  *(uint4*)(op) = make_uint4(p[0], p[1], p[2], p[3]);
  *(uint4*)(op + 4) = make_uint4(p[4], p[5], p[6], p[7]);
}

// hgsum[c] = sum over n of relu(bn2(AGG*inorm))  -- fused BN2+ReLU+readout-sum
__global__ void k_final(const float* __restrict__ AGG, const float* __restrict__ inorm,
                        const float* __restrict__ sc, const float* __restrict__ tc,
                        float* __restrict__ hgsum) {
  __shared__ float sh[256];
  int c = threadIdx.x & (NC - 1);
  int r = threadIdx.x >> 7;
  float scc = sc[c], tcc = tc[c];
  float s = 0.f;
  for (int n = blockIdx.x * 2 + r; n < NN; n += gridDim.x * 2) {
    float a = AGG[(size_t)n * NC + c] * inorm[n];
    s += fmaxf(0.f, fmaf(a, scc, tcc));
  }
  sh[threadIdx.x] = s;
  __syncthreads();
  if (r == 0) unsafeAtomicAdd(&hgsum[c], s + sh[threadIdx.x + 128]);
}

// final batch-BN over hg[8][16] -> out
__global__ void k_out(const float* __restrict__ hgsum, const float* __restrict__ g,
                      const float* __restrict__ bt, float* __restrict__ out) {
  __shared__ float sh[NC];
  int c = threadIdx.x;
  float hg = hgsum[c] * (1.0f / NN);
  sh[c] = hg;
  __syncthreads();
  int d = c & (DD - 1);
  float mu = 0.f;
#pragma unroll
  for (int b = 0; b < BB; b++) mu += sh[b * DD + d];
  mu *= (1.0f / BB);
  float var = 0.f;
#pragma unroll
  for (int b = 0; b < BB; b++) { float t = sh[b * DD + d] - mu; var = fmaf(t, t, var); }
  var *= (1.0f / BB);
  out[c] = fmaf((hg - mu) * rsqrtf(var + EPSBN), g[d], bt[d]);
}

extern "C" void kernel_launch(void* const* d_in, const int* in_sizes, int n_in,
                              void* d_out, int out_size, void* d_ws, size_t ws_size,
                              hipStream_t stream) {
  const float* x   = (const float*)d_in[0];
  const float* W1  = (const float*)d_in[1];
  // d_in[2] = b1: cancels inside BN1 (affine) -- unused
  const float* g1g = (const float*)d_in[3];
  const float* g1b = (const float*)d_in[4];
  const float* W2  = (const float*)d_in[5];
  // d_in[6] = b2: cancels inside BN2 -- unused
  const float* g2g = (const float*)d_in[7];
  const float* g2b = (const float*)d_in[8];
  const float* n1g = (const float*)d_in[9];
  const float* n1b = (const float*)d_in[10];
  const int* src   = (const int*)d_in[11];
  const int* dst   = (const int*)d_in[12];
  float* out = (float*)d_out;

  char* w = (char*)d_ws;
  float* AGG   = (float*)w; w += (size_t)NN * NC * 4;
  ushort* Hb   = (ushort*)w; w += (size_t)NN * NC * 2;
  int* degi    = (int*)w;   w += (size_t)NN * 4;
  int* off     = (int*)w;   w += (size_t)NN * 4;
  ushort* csr  = (ushort*)w; w += (size_t)NE * 2;
  ushort* csrS = (ushort*)w; w += (size_t)NE * 2;
  ushort4* sb  = (ushort4*)w; w += (size_t)NN * 8;
  float* onorm = (float*)w; w += (size_t)NN * 4;
  float* inorm = (float*)w; w += (size_t)NN * 4;
  int* bsum    = (int*)w;   w += (size_t)SCB * 4;
  int* boff    = (int*)w;   w += (size_t)SCB * 4;
  float* sum1  = (float*)w; w += NC * 4;
  float* sq1   = (float*)w; w += NC * 4;
  float* s1    = (float*)w; w += NC * 4;
  float* t1    = (float*)w; w += NC * 4;
  float* sum2  = (float*)w; w += NC * 4;
  float* sq2   = (float*)w; w += NC * 4;
  float* s2    = (float*)w; w += NC * 4;
  float* t2    = (float*)w; w += NC * 4;
  float* hgsum = (float*)w; w += NC * 4;

  // Histogram regions overlay AGG (12.8 MB < 25.6 MB); AGG is first written by
  // k_gather, which runs after k_csr2 has consumed the histograms.
  uint* dstH = (uint*)AGG;
  uint* srcH = dstH + (size_t)G * WPN;

  hipMemsetAsync(sum1, 0, NC * 2 * 4, stream);
  hipMemsetAsync(sum2, 0, NC * 2 * 4, stream);
  hipMemsetAsync(hgsum, 0, NC * 4, stream);

  k_hist<<<2 * G, 256, 0, stream>>>(src, dst, dstH, srcH);
  k_reduce<<<98, 256, 0, stream>>>(dstH, srcH, degi, inorm, onorm);
  k_scan1<<<SCB, 256, 0, stream>>>(degi, bsum);
  k_scan2<<<1, 256, 0, stream>>>(bsum, boff);
  k_scan3<<<SCB, 256, 0, stream>>>(degi, boff, off);
  k_csr2<<<G, 512, 0, stream>>>(src, dst, off, dstH, csr);
  k_shard<<<NN / 4, 256, 0, stream>>>(off, degi, csr, csrS, sb);
  k_gemm1<<<(BB * NN + 255) / 256, 256, 0, stream>>>(x, W1, onorm, Hb);
  k_gather<<<(NN * 16 + 255) / 256, 256, 0, stream>>>(off, sb, csrS, Hb, AGG);
  k_stats<<<512, 256, 0, stream>>>(AGG, inorm, sum1, sq1);
  k_prep<<<1, 128, 0, stream>>>(sum1, sq1, g1g, g1b, s1, t1);
  k_applyg2<<<(BB * NN + 255) / 256, 256, 0, stream>>>(AGG, inorm, onorm, s1, t1, W2, Hb);
  k_gather<<<(NN * 16 + 255) / 256, 256, 0, stream>>>(off, sb, csrS, Hb, AGG);
  k_stats<<<512, 256, 0, stream>>>(AGG, inorm, sum2, sq2);
  k_prep<<<1, 128, 0, stream>>>(sum2, sq2, g2g, g2b, s2, t2);
  k_final<<<512, 256, 0, stream>>>(AGG, inorm, s2, t2, hgsum);
  k_out<<<1, NC, 0, stream>>>(hgsum, n1g, n1b, out);
}

// Round 6
// 230.629 us; speedup vs baseline: 1.2097x; 1.2097x over previous
//
#include <hip/hip_runtime.h>

#define NN 50000
#define NE 800000
#define IND 32
#define DD 16
#define BB 8
#define NC 128   // BB*DD
#define EPSBN 1e-5f
#define SCB ((NN + 255) / 256)   // 196 scan blocks
#define G 128                    // histogram blocks per direction
#define CHE (NE / G)             // 6250 edges per hist block
#define WPN (NN / 4)             // 12500 packed words (4 uint8 counters each)

typedef unsigned int uint;
typedef unsigned short ushort;

__device__ __forceinline__ ushort f2bf(float f) {
  uint u = __float_as_uint(f);
  return (ushort)((u + 0x7fffu + ((u >> 16) & 1u)) >> 16);  // RNE
}
__device__ __forceinline__ uint pack2bf(float lo, float hi) {
  return (uint)f2bf(lo) | ((uint)f2bf(hi) << 16);
}
__device__ __forceinline__ void add8(float* acc, uint4 v) {
  acc[0] += __uint_as_float(v.x << 16);
  acc[1] += __uint_as_float(v.x & 0xffff0000u);
  acc[2] += __uint_as_float(v.y << 16);
  acc[3] += __uint_as_float(v.y & 0xffff0000u);
  acc[4] += __uint_as_float(v.z << 16);
  acc[5] += __uint_as_float(v.z & 0xffff0000u);
  acc[6] += __uint_as_float(v.w << 16);
  acc[7] += __uint_as_float(v.w & 0xffff0000u);
}

// Per-block LDS histogram (uint8 packed 4/word). blocks [0,G): dst, [G,2G): src.
__global__ __launch_bounds__(256) void k_hist(const int* __restrict__ src,
                                              const int* __restrict__ dst,
                                              uint* __restrict__ dstH,
                                              uint* __restrict__ srcH) {
  __shared__ uint h[WPN];  // 50 KB
  int b = blockIdx.x;
  bool isDst = b < G;
  int cb = isDst ? b : b - G;
  const int* idx = isDst ? dst : src;
  uint* out = (isDst ? dstH : srcH) + (size_t)cb * WPN;
  for (int w = threadIdx.x; w < WPN; w += 256) h[w] = 0;
  __syncthreads();
  int base = cb * CHE;
  for (int k = threadIdx.x; k < CHE; k += 256) {
    int d = idx[base + k];
    atomicAdd(&h[d >> 2], 1u << ((d & 3) * 8));
  }
  __syncthreads();
  for (int w = threadIdx.x; w < WPN; w += 256) out[w] = h[w];
}

// Column-reduce the per-block histograms. dst side: also convert dstH in place
// to exclusive per-block byte-prefixes (carry-free packed add: counts <= ~45).
__global__ __launch_bounds__(256) void k_reduce(uint* __restrict__ dstH,
                                                const uint* __restrict__ srcH,
                                                int* __restrict__ degi,
                                                float* __restrict__ inorm,
                                                float* __restrict__ onorm) {
  int b = blockIdx.x;
  bool isDst = b < 49;
  int col = (isDst ? b : b - 49) * 256 + threadIdx.x;
  if (col >= WPN) return;
  if (isDst) {
    uint run = 0;
    for (int k = 0; k < G; k++) {
      size_t p = (size_t)k * WPN + col;
      uint v = dstH[p];
      dstH[p] = run;   // exclusive prefix (packed bytes)
      run += v;
    }
    int n0 = col * 4;
    int4 dv;
    float4 nv;
    int c0 = run & 255, c1 = (run >> 8) & 255, c2 = (run >> 16) & 255, c3 = (run >> 24) & 255;
    dv.x = c0; dv.y = c1; dv.z = c2; dv.w = c3;
    nv.x = rsqrtf((float)(c0 > 1 ? c0 : 1));
    nv.y = rsqrtf((float)(c1 > 1 ? c1 : 1));
    nv.z = rsqrtf((float)(c2 > 1 ? c2 : 1));
    nv.w = rsqrtf((float)(c3 > 1 ? c3 : 1));
    *(int4*)(degi + n0) = dv;
    *(float4*)(inorm + n0) = nv;
  } else {
    uint run = 0;
    for (int k = 0; k < G; k++) run += srcH[(size_t)k * WPN + col];
    int n0 = col * 4;
    float4 nv;
    int c0 = run & 255, c1 = (run >> 8) & 255, c2 = (run >> 16) & 255, c3 = (run >> 24) & 255;
    nv.x = rsqrtf((float)(c0 > 1 ? c0 : 1));
    nv.y = rsqrtf((float)(c1 > 1 ? c1 : 1));
    nv.z = rsqrtf((float)(c2 > 1 ? c2 : 1));
    nv.w = rsqrtf((float)(c3 > 1 ? c3 : 1));
    *(float4*)(onorm + n0) = nv;
  }
}

// ---- hierarchical exclusive scan of degi -> off ----
__global__ void k_scan1(const int* __restrict__ degi, int* __restrict__ bsum) {
  __shared__ int sh[256];
  int n = blockIdx.x * 256 + threadIdx.x;
  sh[threadIdx.x] = (n < NN) ? degi[n] : 0;
  __syncthreads();
  for (int o = 128; o > 0; o >>= 1) {
    if (threadIdx.x < o) sh[threadIdx.x] += sh[threadIdx.x + o];
    __syncthreads();
  }
  if (threadIdx.x == 0) bsum[blockIdx.x] = sh[0];
}

__global__ void k_scan2(const int* __restrict__ bsum, int* __restrict__ boff) {
  __shared__ int sh[256];
  int t = threadIdx.x;
  int v = (t < SCB) ? bsum[t] : 0;
  sh[t] = v;
  __syncthreads();
  for (int o = 1; o < 256; o <<= 1) {
    int u = (t >= o) ? sh[t - o] : 0;
    __syncthreads();
    sh[t] += u;
    __syncthreads();
  }
  if (t < SCB) boff[t] = sh[t] - v;  // exclusive
}

__global__ void k_scan3(const int* __restrict__ degi, const int* __restrict__ boff,
                        int* __restrict__ off) {
  __shared__ int sh[256];
  int n = blockIdx.x * 256 + threadIdx.x;
  int t = threadIdx.x;
  int v = (n < NN) ? degi[n] : 0;
  sh[t] = v;
  __syncthreads();
  for (int o = 1; o < 256; o <<= 1) {
    int u = (t >= o) ? sh[t - o] : 0;
    __syncthreads();
    sh[t] += u;
    __syncthreads();
  }
  if (n < NN) off[n] = boff[blockIdx.x] + sh[t] - v;
}

// CSR build with NO global atomics: pos = off[d] + byte-prefix(block) + LDS rank.
__global__ __launch_bounds__(512) void k_csr2(const int* __restrict__ src,
                                              const int* __restrict__ dst,
                                              const int* __restrict__ off,
                                              const uint* __restrict__ dstH,
                                              ushort* __restrict__ csr) {
  __shared__ uint cur[WPN];  // 50 KB byte cursors
  int b = blockIdx.x;
  for (int w = threadIdx.x; w < WPN; w += 512) cur[w] = 0;
  __syncthreads();
  const uint* bb = dstH + (size_t)b * WPN;
  int base = b * CHE;
  for (int k = threadIdx.x; k < CHE; k += 512) {
    int e = base + k;
    int d = dst[e];
    int sh = (d & 3) * 8;
    uint old = atomicAdd(&cur[d >> 2], 1u << sh);
    int rank = (old >> sh) & 255;
    int pre = (bb[d >> 2] >> sh) & 255;
    csr[off[d] + pre + rank] = (ushort)src[e];
  }
}

// H (bf16, node-major [n][128]) = (x @ W1) * onorm.
// Block 0 also zeroes the 5 contiguous accumulator vectors (sum1..hgsum),
// replacing three hipMemsetAsync dispatches (safe: consumers run later).
__global__ void k_gemm1(const float* __restrict__ x, const float* __restrict__ W1,
                        const float* __restrict__ onorm, ushort* __restrict__ Hb,
                        float* __restrict__ zeroRegion) {
  __shared__ float w[IND * DD];
  int tid = threadIdx.x;
  if (blockIdx.x == 0) {
    for (int i = tid; i < 5 * NC; i += 256) zeroRegion[i] = 0.f;
  }
  for (int i = tid; i < IND * DD; i += 256) w[i] = W1[i];
  __syncthreads();
  int gid = blockIdx.x * 256 + tid;  // gid = b*NN + n
  if (gid >= BB * NN) return;
  int b = gid / NN;
  int n = gid - b * NN;
  const float* xb = x + (size_t)b * IND * NN + n;
  float acc[DD];
#pragma unroll
  for (int d = 0; d < DD; d++) acc[d] = 0.f;
  for (int i = 0; i < IND; i++) {
    float v = xb[(size_t)i * NN];
#pragma unroll
    for (int d = 0; d < DD; d++) acc[d] = fmaf(v, w[i * DD + d], acc[d]);
  }
  float on = onorm[n];
  uint p[8];
#pragma unroll
  for (int k = 0; k < 8; k++) p[k] = pack2bf(acc[2 * k] * on, acc[2 * k + 1] * on);
  uint* o4 = (uint*)(Hb + ((size_t)n * BB + b) * DD);
  *(uint4*)(o4) = make_uint4(p[0], p[1], p[2], p[3]);
  *(uint4*)(o4 + 4) = make_uint4(p[4], p[5], p[6], p[7]);
}

// AGG[n][0:128] (fp32) = sum over in-edges of Hb[src][0:128] (bf16).
// 4-deep unrolled edge loop: 4 independent Hb lines in flight per lane (ILP).
__global__ __launch_bounds__(256) void k_gather(const int* __restrict__ off,
                                                const int* __restrict__ degi,
                                                const ushort* __restrict__ csr,
                                                const ushort* __restrict__ Hb,
                                                float* __restrict__ AGG) {
  int gid = blockIdx.x * 256 + threadIdx.x;
  int n = gid >> 4;
  if (n >= NN) return;
  int q = (gid & 15) * 8;  // 8 bf16 columns per lane, 16 lanes per node
  int o = off[n], dg = degi[n];
  const ushort* hq = Hb + q;
  float acc[8];
#pragma unroll
  for (int k = 0; k < 8; k++) acc[k] = 0.f;
  int j = 0;
  for (; j + 4 <= dg; j += 4) {
    int s0 = csr[o + j], s1 = csr[o + j + 1], s2 = csr[o + j + 2], s3 = csr[o + j + 3];
    uint4 v0 = *(const uint4*)(hq + (size_t)s0 * NC);
    uint4 v1 = *(const uint4*)(hq + (size_t)s1 * NC);
    uint4 v2 = *(const uint4*)(hq + (size_t)s2 * NC);
    uint4 v3 = *(const uint4*)(hq + (size_t)s3 * NC);
    add8(acc, v0);
    add8(acc, v1);
    add8(acc, v2);
    add8(acc, v3);
  }
  for (; j < dg; j++) {
    int s = csr[o + j];
    uint4 v = *(const uint4*)(hq + (size_t)s * NC);
    add8(acc, v);
  }
  float* op = AGG + (size_t)n * NC + q;
  *(float4*)(op) = make_float4(acc[0], acc[1], acc[2], acc[3]);
  *(float4*)(op + 4) = make_float4(acc[4], acc[5], acc[6], acc[7]);
}

// per-column sums of a = AGG*inorm  (for BN stats)
__global__ void k_stats(const float* __restrict__ AGG, const float* __restrict__ inorm,
                        float* __restrict__ sum, float* __restrict__ sumsq) {
  __shared__ float sh[256];
  int c = threadIdx.x & (NC - 1);
  int r = threadIdx.x >> 7;
  float s = 0.f, ss = 0.f;
  for (int n = blockIdx.x * 2 + r; n < NN; n += gridDim.x * 2) {
    float a = AGG[(size_t)n * NC + c] * inorm[n];
    s += a;
    ss = fmaf(a, a, ss);
  }
  sh[threadIdx.x] = s;
  __syncthreads();
  if (r == 0) unsafeAtomicAdd(&sum[c], s + sh[threadIdx.x + 128]);
  __syncthreads();
  sh[threadIdx.x] = ss;
  __syncthreads();
  if (r == 0) unsafeAtomicAdd(&sumsq[c], ss + sh[threadIdx.x + 128]);
}

// Hb = bf16((relu(bn1(AGG*inorm)) @ W2) * onorm)
// BN fold (prep) computed in-block from sum/sumsq (k_prep eliminated).
__global__ void k_applyg2(const float* __restrict__ AGG, const float* __restrict__ inorm,
                          const float* __restrict__ onorm, const float* __restrict__ sum,
                          const float* __restrict__ sumsq, const float* __restrict__ gamma,
                          const float* __restrict__ beta, const float* __restrict__ W2,
                          ushort* __restrict__ Hb) {
  __shared__ float w[DD * DD];
  __shared__ float ssc[NC], stc[NC];
  int tid = threadIdx.x;
  if (tid < DD * DD) w[tid] = W2[tid];
  if (tid < NC) {
    float mu = sum[tid] * (1.0f / NN);
    float var = fmaxf(sumsq[tid] * (1.0f / NN) - mu * mu, 0.f);
    int d = tid & (DD - 1);
    float s = gamma[d] * rsqrtf(var + EPSBN);
    ssc[tid] = s;
    stc[tid] = beta[d] - mu * s;
  }
  __syncthreads();
  int gid = blockIdx.x * 256 + tid;  // gid = n*8 + b
  if (gid >= BB * NN) return;
  int n = gid >> 3, b = gid & 7;
  const float4* ap = (const float4*)(AGG + (size_t)gid * DD);
  float inn = inorm[n];
  float z[DD];
  float4 v0 = ap[0], v1 = ap[1], v2 = ap[2], v3 = ap[3];
  z[0] = v0.x; z[1] = v0.y; z[2] = v0.z; z[3] = v0.w;
  z[4] = v1.x; z[5] = v1.y; z[6] = v1.z; z[7] = v1.w;
  z[8] = v2.x; z[9] = v2.y; z[10] = v2.z; z[11] = v2.w;
  z[12] = v3.x; z[13] = v3.y; z[14] = v3.z; z[15] = v3.w;
#pragma unroll
  for (int d = 0; d < DD; d++) {
    int c = b * DD + d;
    z[d] = fmaxf(0.f, fmaf(z[d] * inn, ssc[c], stc[c]));
  }
  float on = onorm[n];
  float o[DD];
#pragma unroll
  for (int d2 = 0; d2 < DD; d2++) {
    float acc = 0.f;
#pragma unroll
    for (int d = 0; d < DD; d++) acc = fmaf(z[d], w[d * DD + d2], acc);
    o[d2] = acc * on;
  }
  uint p[8];
#pragma unroll
  for (int k = 0; k < 8; k++) p[k] = pack2bf(o[2 * k], o[2 * k + 1]);
  uint* op = (uint*)(Hb + (size_t)gid * DD);
  *(uint4*)(op) = make_uint4(p[0], p[1], p[2], p[3]);
  *(uint4*)(op + 4) = make_uint4(p[4], p[5], p[6], p[7]);
}

// hgsum[c] = sum over n of relu(bn2(AGG*inorm)); BN fold computed in-block.
__global__ void k_final(const float* __restrict__ AGG, const float* __restrict__ inorm,
                        const float* __restrict__ sum, const float* __restrict__ sumsq,
                        const float* __restrict__ gamma, const float* __restrict__ beta,
                        float* __restrict__ hgsum) {
  __shared__ float sh[256];
  __shared__ float ssc[NC], stc[NC];
  int tid = threadIdx.x;
  if (tid < NC) {
    float mu = sum[tid] * (1.0f / NN);
    float var = fmaxf(sumsq[tid] * (1.0f / NN) - mu * mu, 0.f);
    int d = tid & (DD - 1);
    float s = gamma[d] * rsqrtf(var + EPSBN);
    ssc[tid] = s;
    stc[tid] = beta[d] - mu * s;
  }
  __syncthreads();
  int c = tid & (NC - 1);
  int r = tid >> 7;
  float scc = ssc[c], tcc = stc[c];
  float s = 0.f;
  for (int n = blockIdx.x * 2 + r; n < NN; n += gridDim.x * 2) {
    float a = AGG[(size_t)n * NC + c] * inorm[n];
    s += fmaxf(0.f, fmaf(a, scc, tcc));
  }
  sh[tid] = s;
  __syncthreads();
  if (r == 0) unsafeAtomicAdd(&hgsum[c], s + sh[tid + 128]);
}

// final batch-BN over hg[8][16] -> out
__global__ void k_out(const float* __restrict__ hgsum, const float* __restrict__ g,
                      const float* __restrict__ bt, float* __restrict__ out) {
  __shared__ float sh[NC];
  int c = threadIdx.x;
  float hg = hgsum[c] * (1.0f / NN);
  sh[c] = hg;
  __syncthreads();
  int d = c & (DD - 1);
  float mu = 0.f;
#pragma unroll
  for (int b = 0; b < BB; b++) mu += sh[b * DD + d];
  mu *= (1.0f / BB);
  float var = 0.f;
#pragma unroll
  for (int b = 0; b < BB; b++) { float t = sh[b * DD + d] - mu; var = fmaf(t, t, var); }
  var *= (1.0f / BB);
  out[c] = fmaf((hg - mu) * rsqrtf(var + EPSBN), g[d], bt[d]);
}

extern "C" void kernel_launch(void* const* d_in, const int* in_sizes, int n_in,
                              void* d_out, int out_size, void* d_ws, size_t ws_size,
                              hipStream_t stream) {
  const float* x   = (const float*)d_in[0];
  const float* W1  = (const float*)d_in[1];
  // d_in[2] = b1: cancels inside BN1 (affine) -- unused
  const float* g1g = (const float*)d_in[3];
  const float* g1b = (const float*)d_in[4];
  const float* W2  = (const float*)d_in[5];
  // d_in[6] = b2: cancels inside BN2 -- unused
  const float* g2g = (const float*)d_in[7];
  const float* g2b = (const float*)d_in[8];
  const float* n1g = (const float*)d_in[9];
  const float* n1b = (const float*)d_in[10];
  const int* src   = (const int*)d_in[11];
  const int* dst   = (const int*)d_in[12];
  float* out = (float*)d_out;

  char* w = (char*)d_ws;
  float* AGG   = (float*)w; w += (size_t)NN * NC * 4;
  ushort* Hb   = (ushort*)w; w += (size_t)NN * NC * 2;
  int* degi    = (int*)w;   w += (size_t)NN * 4;
  int* off     = (int*)w;   w += (size_t)NN * 4;
  ushort* csr  = (ushort*)w; w += (size_t)NE * 2;
  float* onorm = (float*)w; w += (size_t)NN * 4;
  float* inorm = (float*)w; w += (size_t)NN * 4;
  int* bsum    = (int*)w;   w += (size_t)SCB * 4;
  int* boff    = (int*)w;   w += (size_t)SCB * 4;
  // 5 contiguous accumulator vectors (zeroed by k_gemm1 block 0):
  float* sum1  = (float*)w; w += NC * 4;
  float* sq1   = (float*)w; w += NC * 4;
  float* sum2  = (float*)w; w += NC * 4;
  float* sq2   = (float*)w; w += NC * 4;
  float* hgsum = (float*)w; w += NC * 4;

  // Histogram regions overlay AGG (12.8 MB < 25.6 MB); AGG is first written by
  // k_gather, which runs after k_csr2 has consumed the histograms.
  uint* dstH = (uint*)AGG;
  uint* srcH = dstH + (size_t)G * WPN;

  k_hist<<<2 * G, 256, 0, stream>>>(src, dst, dstH, srcH);
  k_reduce<<<98, 256, 0, stream>>>(dstH, srcH, degi, inorm, onorm);
  k_scan1<<<SCB, 256, 0, stream>>>(degi, bsum);
  k_scan2<<<1, 256, 0, stream>>>(bsum, boff);
  k_scan3<<<SCB, 256, 0, stream>>>(degi, boff, off);
  k_csr2<<<G, 512, 0, stream>>>(src, dst, off, dstH, csr);
  k_gemm1<<<(BB * NN + 255) / 256, 256, 0, stream>>>(x, W1, onorm, Hb, sum1);
  k_gather<<<(NN * 16 + 255) / 256, 256, 0, stream>>>(off, degi, csr, Hb, AGG);
  k_stats<<<512, 256, 0, stream>>>(AGG, inorm, sum1, sq1);
  k_applyg2<<<(BB * NN + 255) / 256, 256, 0, stream>>>(AGG, inorm, onorm, sum1, sq1,
                                                       g1g, g1b, W2, Hb);
  k_gather<<<(NN * 16 + 255) / 256, 256, 0, stream>>>(off, degi, csr, Hb, AGG);
  k_stats<<<512, 256, 0, stream>>>(AGG, inorm, sum2, sq2);
  k_final<<<512, 256, 0, stream>>>(AGG, inorm, sum2, sq2, g2g, g2b, hgsum);
  k_out<<<1, NC, 0, stream>>>(hgsum, n1g, n1b, out);
}